// Round 13
// baseline (650.035 us; speedup 1.0000x reference)
//
#include <hip/hip_runtime.h>
#include <hip/hip_bf16.h>

typedef unsigned short u16;
typedef unsigned int u32;
typedef short short8v __attribute__((ext_vector_type(8)));
typedef float f32x4 __attribute__((ext_vector_type(4)));
typedef u32 u32x2 __attribute__((ext_vector_type(2)));

#define NN 50000
#define EE 800000
#define PP 65536
#define NB 196  // ceil(NN/256)

// ---- static device workspace. RULE (r3): device-global addresses never cross
// the host/device boundary — kernels resolve them via compile-time IDs.
__device__ __align__(256) float g_deg_norm[NN];
__device__ __align__(256) int   g_row_ptr[NN + 1];
__device__ __align__(256) int   g_deg[NN];
__device__ __align__(256) int   g_rank[EE];        // intra-row rank from count_deg
__device__ __align__(256) int   g_bsum[256];
__device__ __align__(256) int   g_boff[256];
__device__ __align__(256) u32   g_ecwp[EE];        // packed edge: col(16b) | w_bf16(16b)
__device__ __align__(256) u16   g_X16[NN * 128];   // x bf16, row-major
__device__ __align__(256) u16   g_H1[NN * 128];    // hop outputs, stride 128
__device__ __align__(256) u16   g_H2[NN * 128];
__device__ __align__(256) u16   g_H3[NN * 128];
__device__ __align__(256) u16   g_Hn0[NN * 128];
__device__ __align__(256) u16   g_Hn1[NN * 128];
__device__ __align__(256) u16   g_Hf16[NN * 64];   // final h (bf16), row-major
__device__ __align__(256) u16   g_Bf1[512 * 128];  // W in MFMA B-fragment order
__device__ __align__(256) u16   g_Bf2[512 * 128];
__device__ __align__(256) u16   g_Bf3[512 * 64];
__device__ __align__(256) u16   g_Pf1[4 * 64 * 8]; // P1 in B-frag order
__device__ int g_f32mode;  // 1 if harness float tensors are float32, 0 if bf16

__device__ __forceinline__ float bf2f(u16 u) {
  union { u32 i; float f; } v;
  v.i = ((u32)u) << 16;
  return v.f;
}
__device__ __forceinline__ u16 f2bf(float f) {
  u32 x = __float_as_uint(f);
  u32 r = (x + 0x7fffu + ((x >> 16) & 1u)) >> 16;  // RNE
  return (u16)r;
}
__device__ __forceinline__ float ldf(const void* p, int i, int m) {
  return m ? ((const float*)p)[i] : bf2f(((const u16*)p)[i]);
}

// buffer IDs: 0 = X16, 3 = Hn0, 4 = Hn1, 5 = H1, 6 = H2, 7 = H3 (stride 128)
template <int ID>
__device__ __forceinline__ u16* sel_buf() {
  if (ID == 0) return g_X16;
  if (ID == 3) return g_Hn0;
  if (ID == 4) return g_Hn1;
  if (ID == 5) return g_H1;
  if (ID == 6) return g_H2;
  return g_H3;
}
template <int ID>
__device__ __forceinline__ u16* sel_bf() {
  if (ID == 1) return g_Bf1;
  if (ID == 2) return g_Bf2;
  return g_Bf3;
}

// -------------------------------------------------------------- dtype probe
__global__ void probe_dtype_kernel(const u16* __restrict__ x) {
  __shared__ int cnt;
  if (threadIdx.x == 0) cnt = 0;
  __syncthreads();
  int c = 0;
  for (int i = threadIdx.x; i < 2048; i += 256) {
    u16 u = x[2 * i];
    int e = (u >> 7) & 0xFF;
    if (e >= 0x8F) c++;
  }
  atomicAdd(&cnt, c);
  __syncthreads();
  if (threadIdx.x == 0) g_f32mode = (cnt > 64) ? 1 : 0;
}

// ---------------------------------------------------------- x -> bf16 convert
__global__ void convert_x_kernel(const void* __restrict__ x) {
  int m = g_f32mode;
  int i = blockIdx.x * 256 + threadIdx.x;  // u32-pair index
  if (i >= NN * 64) return;
  u32 lo = f2bf(ldf(x, 2 * i, m));
  u32 hi = f2bf(ldf(x, 2 * i + 1, m));
  ((u32*)g_X16)[i] = lo | (hi << 16);
}

// ---------------- fused: W1/W2/W3 -> B-frag order, P1 -> B-frag, zero g_deg
template <int FOUT>
__device__ __forceinline__ void conv_w_body(const void* W, u16* dstbuf, int t, int m) {
  constexpr int NT = FOUT / 16;
  if (t >= 1024 * NT) return;
  int lane = t & 63;
  int rest = t >> 6;
  int nt = rest % NT;
  int s = (rest / NT) % 4;
  int kc = rest / (NT * 4);
  int kbase = kc * 128 + s * 32 + ((lane >> 4) << 3);
  int n = nt * 16 + (lane & 15);
  u16* dst = dstbuf + (size_t)t * 8;
#pragma unroll
  for (int j = 0; j < 8; ++j) dst[j] = f2bf(ldf(W, (kbase + j) * FOUT + n, m));
}
__global__ void convert_wp_kernel(const void* __restrict__ W1, const void* __restrict__ W2,
                                  const void* __restrict__ W3, const void* __restrict__ P1) {
  int m = g_f32mode;
  int b = blockIdx.x, tid = threadIdx.x;
  if (b < 32) {
    conv_w_body<128>(W1, g_Bf1, b * 256 + tid, m);
  } else if (b < 64) {
    conv_w_body<128>(W2, g_Bf2, (b - 32) * 256 + tid, m);
  } else if (b < 80) {
    conv_w_body<64>(W3, g_Bf3, (b - 64) * 256 + tid, m);
  } else if (b == 80) {
    int f = tid >> 6, lane = tid & 63;
    int ks = f >> 1, nt = f & 1;
    int quad = lane >> 4, arow = lane & 15;
#pragma unroll
    for (int j = 0; j < 8; ++j)
      g_Pf1[(size_t)tid * 8 + j] =
          f2bf(ldf(P1, (ks * 32 + quad * 8 + j) * 32 + nt * 16 + arow, m));
  } else {
    int i = (b - 81) * 256 + tid;
    if (i < NN) g_deg[i] = 0;
  }
}

// ---------------------------------------------------------------- CSR build
__global__ void count_deg_kernel(const int* __restrict__ dst) {
  int e = blockIdx.x * blockDim.x + threadIdx.x;
  if (e < EE) g_rank[e] = atomicAdd(&g_deg[dst[e]], 1);
}
__global__ __launch_bounds__(256) void deg_partial_kernel() {
  __shared__ int ws[4];
  int b = blockIdx.x, t = threadIdx.x;
  int i = b * 256 + t;
  int v = (i < NN) ? g_deg[i] : 0;
  if (i < NN) g_deg_norm[i] = rsqrtf((float)(v > 0 ? v : 1));
  int x = v;
#pragma unroll
  for (int off = 1; off < 64; off <<= 1) x += __shfl_xor(x, off, 64);
  if ((t & 63) == 0) ws[t >> 6] = x;
  __syncthreads();
  if (t == 0) g_bsum[b] = ws[0] + ws[1] + ws[2] + ws[3];
}
__global__ __launch_bounds__(256) void scan_bsum_kernel() {
  __shared__ int ws[4];
  int t = threadIdx.x;
  int v = (t < NB) ? g_bsum[t] : 0;
  int x = v;
#pragma unroll
  for (int off = 1; off < 64; off <<= 1) {
    int y = __shfl_up(x, off, 64);
    if ((t & 63) >= off) x += y;
  }
  if ((t & 63) == 63) ws[t >> 6] = x;
  __syncthreads();
  int wp = 0;
  if (t >= 64) wp += ws[0];
  if (t >= 128) wp += ws[1];
  if (t >= 192) wp += ws[2];
  if (t < NB) g_boff[t] = wp + x - v;  // exclusive
}
__global__ __launch_bounds__(256) void rowptr_kernel() {
  __shared__ int ws[4];
  int b = blockIdx.x, t = threadIdx.x;
  int i = b * 256 + t;
  int v = (i < NN) ? g_deg[i] : 0;
  int x = v;
#pragma unroll
  for (int off = 1; off < 64; off <<= 1) {
    int y = __shfl_up(x, off, 64);
    if ((t & 63) >= off) x += y;
  }
  if ((t & 63) == 63) ws[t >> 6] = x;
  __syncthreads();
  int wp = g_boff[b];
  if (t >= 64) wp += ws[0];
  if (t >= 128) wp += ws[1];
  if (t >= 192) wp += ws[2];
  if (i < NN) g_row_ptr[i] = wp + x - v;
  if (b == 0 && t == 0) g_row_ptr[NN] = EE;
}
__global__ void fill_csr_kernel(const int* __restrict__ src, const int* __restrict__ dst,
                                const void* __restrict__ w_edge) {
  int m = g_f32mode;
  int e = blockIdx.x * blockDim.x + threadIdx.x;
  if (e >= EE) return;
  int d = dst[e], s = src[e];
  int slot = g_row_ptr[d] + g_rank[e];  // no atomic
  float w = ldf(w_edge, e, m) * g_deg_norm[s];
  g_ecwp[slot] = (u32)s | ((u32)f2bf(w) << 16);
}

// ------------------------------------------------------------------- one hop
// out[n][f] = deg_norm[n] * sum_e w[e] * in[col[e]][f]
// r13: TWO edges per VMEM instruction. Wave halves (h = lane>>5); lane l5 of
// half h gathers dwordx2 (4 features) of edge 2i+h's row -> 64 lanes x 8 B =
// two full 256-B rows per instruction. 8-deep unroll = 16 edges in flight.
// Cross-half shfl_xor(32) combine; lanes 0-31 store dwordx2.
template <int IN_ID, int OUT_ID>
__global__ __launch_bounds__(256) void hop_kernel() {
  int n = blockIdx.x * 4 + (threadIdx.x >> 6);
  if (n >= NN) return;
  int lane = threadIdx.x & 63;
  int h = lane >> 5, l5 = lane & 31;
  const u16* buf = sel_buf<IN_ID>();
  const u32x2* inf = (const u32x2*)(buf) + l5;  // row r: inf + r*32 (u32x2 units)
  int beg = g_row_ptr[n], end = g_row_ptr[n + 1];
  float a[8][4];
#pragma unroll
  for (int i = 0; i < 8; ++i)
#pragma unroll
    for (int f = 0; f < 4; ++f) a[i][f] = 0.f;

  int e = beg;
  for (; e + 16 <= end; e += 16) {
    u32 pw = g_ecwp[e + (lane & 15)];  // 16 records, coalesced 64 B
    u32 rec[8];
#pragma unroll
    for (int i = 0; i < 8; ++i) rec[i] = __shfl((int)pw, 2 * i + h, 16);
    u32x2 v[8];
#pragma unroll
    for (int i = 0; i < 8; ++i) v[i] = inf[(rec[i] & 0xFFFFu) * 32];
#pragma unroll
    for (int i = 0; i < 8; ++i) {
      float w = bf2f((u16)(rec[i] >> 16));
      a[i][0] += w * bf2f((u16)v[i].x);
      a[i][1] += w * bf2f((u16)(v[i].x >> 16));
      a[i][2] += w * bf2f((u16)v[i].y);
      a[i][3] += w * bf2f((u16)(v[i].y >> 16));
    }
  }
  for (; e + 8 <= end; e += 8) {
    u32 pw = g_ecwp[e + (lane & 7)];
    u32 rec[4];
#pragma unroll
    for (int i = 0; i < 4; ++i) rec[i] = __shfl((int)pw, 2 * i + h, 8);
    u32x2 v[4];
#pragma unroll
    for (int i = 0; i < 4; ++i) v[i] = inf[(rec[i] & 0xFFFFu) * 32];
#pragma unroll
    for (int i = 0; i < 4; ++i) {
      float w = bf2f((u16)(rec[i] >> 16));
      a[i][0] += w * bf2f((u16)v[i].x);
      a[i][1] += w * bf2f((u16)(v[i].x >> 16));
      a[i][2] += w * bf2f((u16)v[i].y);
      a[i][3] += w * bf2f((u16)(v[i].y >> 16));
    }
  }
  for (; e < end; e += 2) {
    int idx = e + h;
    u32 rec = (idx < end) ? g_ecwp[idx] : 0u;  // w = bf16(0) = 0 -> no contribution
    u32x2 v = inf[(rec & 0xFFFFu) * 32];       // col 0 safe
    float w = bf2f((u16)(rec >> 16));
    a[0][0] += w * bf2f((u16)v.x);
    a[0][1] += w * bf2f((u16)(v.x >> 16));
    a[0][2] += w * bf2f((u16)v.y);
    a[0][3] += w * bf2f((u16)(v.y >> 16));
  }

  float s[4];
#pragma unroll
  for (int f = 0; f < 4; ++f) {
    s[f] = ((a[0][f] + a[1][f]) + (a[2][f] + a[3][f])) +
           ((a[4][f] + a[5][f]) + (a[6][f] + a[7][f]));
    s[f] += __shfl_xor(s[f], 32, 64);  // combine halves
  }
  if (h == 0) {
    float dn = g_deg_norm[n];
    u32x2 o;
    o.x = (u32)f2bf(s[0] * dn) | ((u32)f2bf(s[1] * dn) << 16);
    o.y = (u32)f2bf(s[2] * dn) | ((u32)f2bf(s[3] * dn) << 16);
    *((u32x2*)(sel_buf<OUT_ID>() + n * 128) + l5) = o;
  }
}

// ------------------------------------------------------------------ MFMA GEMM
// C(M x FOUT) = [f0 | H1 | H2 | H3] (Mx512, row-major) @ B + bias, opt ReLU.
// 64 rows/block (wave = one 16-row m-tile), grid 782 -> ~12 waves/CU (r12-proven).
template <int FOUT, bool RELU, int A0_ID, int C_ID, int BF_ID>
__global__ __launch_bounds__(256) void gemm_kernel(const void* __restrict__ bias,
                                                   void* __restrict__ outp) {
  constexpr int NT = FOUT / 16;
  const u16* Bf = sel_bf<BF_ID>();
  int tid = threadIdx.x;
  int lane = tid & 63, wv = tid >> 6;
  int quad = lane >> 4, arow = lane & 15;
  int mbase = blockIdx.x * 64 + wv * 16;
  if (mbase >= NN) return;  // no barriers in kernel -> safe (NN % 16 == 0)
  int row0 = mbase + arow;

  f32x4 acc[NT];
#pragma unroll
  for (int nt = 0; nt < NT; ++nt) acc[nt] = (f32x4){0.f, 0.f, 0.f, 0.f};

#pragma unroll
  for (int kc = 0; kc < 4; ++kc) {
    const u16* base = (kc == 0) ? sel_buf<A0_ID>() : (kc == 1) ? g_H1 : (kc == 2) ? g_H2 : g_H3;
#pragma unroll
    for (int s = 0; s < 4; ++s) {
      int ko = s * 32 + quad * 8;
      short8v av = *(const short8v*)(base + row0 * 128 + ko);
      const u16* bp = Bf + (size_t)(((kc * 4 + s) * NT) * 64 + lane) * 8;
#pragma unroll
      for (int nt = 0; nt < NT; ++nt) {
        short8v b = *(const short8v*)(bp + nt * 64 * 8);
        acc[nt] = __builtin_amdgcn_mfma_f32_16x16x32_bf16(av, b, acc[nt], 0, 0, 0);
      }
    }
  }

  int m = g_f32mode;
  float bn[NT];
#pragma unroll
  for (int nt = 0; nt < NT; ++nt) bn[nt] = ldf(bias, nt * 16 + arow, m);
#pragma unroll
  for (int i = 0; i < 4; ++i) {
    int row = mbase + quad * 4 + i;  // C/D: col=lane&15, row=quad*4+reg
#pragma unroll
    for (int nt = 0; nt < NT; ++nt) {
      float v = acc[nt][i] + bn[nt];
      if (RELU) v = v > 0.f ? v : 0.f;
      int ci = row * FOUT + nt * 16 + arow;
      if (C_ID == 0) {
        g_Hf16[ci] = f2bf(v);
        if (m) ((float*)outp)[2 * PP + ci] = v;
        else   ((u16*)outp)[2 * PP + ci] = f2bf(v);
      } else {
        sel_buf<C_ID>()[ci] = f2bf(v);
      }
    }
  }
}

// ------------------------------------------------------------------ predictor
// MFMA predictor (r11-proven). One wave = 16 pairs.
__global__ __launch_bounds__(256) void predictor_kernel(
    const int* __restrict__ pos_src, const int* __restrict__ pos_dst,
    const int* __restrict__ neg_src, const int* __restrict__ neg_dst,
    const void* __restrict__ pb1, const void* __restrict__ P2,
    const void* __restrict__ pb2, const void* __restrict__ P3, const void* __restrict__ pb3,
    void* __restrict__ out) {
  __shared__ float sP2[32 * 16];
  __shared__ float sb1[32], sb2[16], sP3[16];
  __shared__ float sb3;
  __shared__ float zt[4][16][33];
  int m = g_f32mode;
  int tid = threadIdx.x;
  for (int i = tid; i < 512; i += 256) sP2[i] = ldf(P2, i, m);
  if (tid < 32) sb1[tid] = ldf(pb1, tid, m);
  if (tid < 16) sb2[tid] = ldf(pb2, tid, m);
  if (tid < 16) sP3[tid] = ldf(P3, tid, m);
  if (tid == 0) sb3 = ldf(pb3, 0, m);
  __syncthreads();

  int wv = tid >> 6, lane = tid & 63;
  int quad = lane >> 4, arow = lane & 15;
  int base = (blockIdx.x * 4 + wv) * 16;
  int idx = base + arow;
  int s, d;
  if (idx < PP) { s = pos_src[idx]; d = pos_dst[idx]; }  // PP%16==0 -> wave-uniform
  else          { s = neg_src[idx - PP]; d = neg_dst[idx - PP]; }

  const u16* hs = g_Hf16 + s * 64 + quad * 8;
  const u16* hd = g_Hf16 + d * 64 + quad * 8;
  short8v zf[2];
#pragma unroll
  for (int ks = 0; ks < 2; ++ks) {
    short8v a = *(const short8v*)(hs + ks * 32);
    short8v b = *(const short8v*)(hd + ks * 32);
#pragma unroll
    for (int j = 0; j < 8; ++j)
      ((u16*)&zf[ks])[j] = f2bf(bf2f((u16)a[j]) * bf2f((u16)b[j]));
  }
  f32x4 acc[2];
  acc[0] = (f32x4){0.f, 0.f, 0.f, 0.f};
  acc[1] = (f32x4){0.f, 0.f, 0.f, 0.f};
#pragma unroll
  for (int ks = 0; ks < 2; ++ks) {
#pragma unroll
    for (int nt = 0; nt < 2; ++nt) {
      short8v bfr = *(const short8v*)(g_Pf1 + (size_t)((ks * 2 + nt) * 64 + lane) * 8);
      acc[nt] = __builtin_amdgcn_mfma_f32_16x16x32_bf16(zf[ks], bfr, acc[nt], 0, 0, 0);
    }
  }
#pragma unroll
  for (int nt = 0; nt < 2; ++nt) {
    float bn = sb1[nt * 16 + arow];
#pragma unroll
    for (int i = 0; i < 4; ++i) {
      float v = acc[nt][i] + bn;
      zt[wv][quad * 4 + i][nt * 16 + arow] = v > 0.f ? v : 0.2f * v;
    }
  }
  __syncthreads();
  float z2[4];
#pragma unroll
  for (int jj = 0; jj < 4; ++jj) z2[jj] = sb2[quad * 4 + jj];
  const float* zrow = &zt[wv][arow][0];
#pragma unroll
  for (int c = 0; c < 32; ++c) {
    float zc = zrow[c];
#pragma unroll
    for (int jj = 0; jj < 4; ++jj) z2[jj] += zc * sP2[c * 16 + quad * 4 + jj];
  }
  float o = 0.f;
#pragma unroll
  for (int jj = 0; jj < 4; ++jj) {
    float v = z2[jj] > 0.f ? z2[jj] : 0.2f * z2[jj];
    o += v * sP3[quad * 4 + jj];
  }
  o += __shfl_xor(o, 16, 64);
  o += __shfl_xor(o, 32, 64);
  o += sb3;
  if (quad == 0) {
    if (m) ((float*)out)[idx] = o;
    else   ((u16*)out)[idx] = f2bf(o);
  }
}

// ------------------------------------------------------------------- launch
extern "C" void kernel_launch(void* const* d_in, const int* in_sizes, int n_in,
                              void* d_out, int out_size, void* d_ws, size_t ws_size,
                              hipStream_t stream) {
  const u16* x       = (const u16*)d_in[0];
  const int* src     = (const int*)d_in[1];
  const int* dst     = (const int*)d_in[2];
  const void* w_edge = d_in[3];
  const int* pos_src = (const int*)d_in[4];
  const int* pos_dst = (const int*)d_in[5];
  const int* neg_src = (const int*)d_in[6];
  const int* neg_dst = (const int*)d_in[7];
  const void* W1 = d_in[8];
  const void* b1 = d_in[9];
  const void* W2 = d_in[10];
  const void* b2 = d_in[11];
  const void* W3 = d_in[12];
  const void* b3 = d_in[13];
  const void* P1  = d_in[14];
  const void* pb1 = d_in[15];
  const void* P2  = d_in[16];
  const void* pb2 = d_in[17];
  const void* P3  = d_in[18];
  const void* pb3 = d_in[19];
  (void)d_ws; (void)ws_size; (void)in_sizes; (void)n_in; (void)out_size;

  // --- probe + pre-conversion (fused) + CSR build ---
  probe_dtype_kernel<<<1, 256, 0, stream>>>(x);
  convert_x_kernel<<<(NN * 64 + 255) / 256, 256, 0, stream>>>(x);
  convert_wp_kernel<<<81 + NB, 256, 0, stream>>>(W1, W2, W3, P1);  // + zero g_deg
  count_deg_kernel<<<(EE + 255) / 256, 256, 0, stream>>>(dst);
  deg_partial_kernel<<<NB, 256, 0, stream>>>();
  scan_bsum_kernel<<<1, 256, 0, stream>>>();
  rowptr_kernel<<<NB, 256, 0, stream>>>();
  fill_csr_kernel<<<(EE + 255) / 256, 256, 0, stream>>>(src, dst, w_edge);

  int gHop = (NN + 3) / 4;
  int gGemm = (NN + 63) / 64;

  // --- Layer 1: f0 = x(bf16) ---
  hop_kernel<0, 5><<<gHop, 256, 0, stream>>>();
  hop_kernel<5, 6><<<gHop, 256, 0, stream>>>();
  hop_kernel<6, 7><<<gHop, 256, 0, stream>>>();
  gemm_kernel<128, true, 0, 3, 1><<<gGemm, 256, 0, stream>>>(b1, nullptr);

  // --- Layer 2: f0 = Hn0 ---
  hop_kernel<3, 5><<<gHop, 256, 0, stream>>>();
  hop_kernel<5, 6><<<gHop, 256, 0, stream>>>();
  hop_kernel<6, 7><<<gHop, 256, 0, stream>>>();
  gemm_kernel<128, true, 3, 4, 2><<<gGemm, 256, 0, stream>>>(b2, nullptr);

  // --- Layer 3: f0 = Hn1, no relu, writes g_Hf16 + out h-region ---
  hop_kernel<4, 5><<<gHop, 256, 0, stream>>>();
  hop_kernel<5, 6><<<gHop, 256, 0, stream>>>();
  hop_kernel<6, 7><<<gHop, 256, 0, stream>>>();
  gemm_kernel<64, false, 4, 0, 3><<<gGemm, 256, 0, stream>>>(b3, d_out);

  // --- Predictor (pos+neg fused, MFMA) ---
  predictor_kernel<<<(2 * PP) / (4 * 16), 256, 0, stream>>>(pos_src, pos_dst, neg_src, neg_dst,
                                                            pb1, P2, pb2, P3, pb3, d_out);
}

// Round 14
// 523.951 us; speedup vs baseline: 1.2406x; 1.2406x over previous
//
#include <hip/hip_runtime.h>
#include <hip/hip_bf16.h>

typedef unsigned short u16;
typedef unsigned int u32;
typedef short short8v __attribute__((ext_vector_type(8)));
typedef float f32x4 __attribute__((ext_vector_type(4)));

#define NN 50000
#define EE 800000
#define PP 65536
#define NB 196  // ceil(NN/256)

// ---- static device workspace. RULE (r3): device-global addresses never cross
// the host/device boundary — kernels resolve them via compile-time IDs.
__device__ __align__(256) float g_deg_norm[NN];
__device__ __align__(256) int   g_row_ptr[NN + 1];
__device__ __align__(256) int   g_deg[NN];
__device__ __align__(256) int   g_rank[EE];        // intra-row rank from count_deg
__device__ __align__(256) int   g_bsum[256];
__device__ __align__(256) int   g_boff[256];
__device__ __align__(256) u32   g_ecwp[EE];        // packed edge: col(16b) | w_bf16(16b)
__device__ __align__(256) u16   g_X16[NN * 128];   // x bf16, row-major
__device__ __align__(256) u16   g_H1[NN * 128];    // hop outs / 2x Z (layer-3 Horner)
__device__ __align__(256) u16   g_H2[NN * 128];
__device__ __align__(256) u16   g_H3[NN * 128];
__device__ __align__(256) u16   g_Hn0[NN * 128];
__device__ __align__(256) u16   g_Hn1[NN * 128];
__device__ __align__(256) u16   g_Hf16[NN * 64];   // final h (bf16), row-major
__device__ __align__(256) u16   g_Bf1[512 * 128];  // W in MFMA B-fragment order
__device__ __align__(256) u16   g_Bf2[512 * 128];
__device__ __align__(256) u16   g_Bf3[512 * 64];
__device__ __align__(256) u16   g_Pf1[4 * 64 * 8]; // P1 in B-frag order
__device__ int g_f32mode;  // 1 if harness float tensors are float32, 0 if bf16

__device__ __forceinline__ float bf2f(u16 u) {
  union { u32 i; float f; } v;
  v.i = ((u32)u) << 16;
  return v.f;
}
__device__ __forceinline__ u16 f2bf(float f) {
  u32 x = __float_as_uint(f);
  u32 r = (x + 0x7fffu + ((x >> 16) & 1u)) >> 16;  // RNE
  return (u16)r;
}
__device__ __forceinline__ float ldf(const void* p, int i, int m) {
  return m ? ((const float*)p)[i] : bf2f(((const u16*)p)[i]);
}

// buffer IDs: 0 = X16, 3 = Hn0, 4 = Hn1, 5 = H1, 6 = H2, 7 = H3 (stride 128)
template <int ID>
__device__ __forceinline__ u16* sel_buf() {
  if (ID == 0) return g_X16;
  if (ID == 3) return g_Hn0;
  if (ID == 4) return g_Hn1;
  if (ID == 5) return g_H1;
  if (ID == 6) return g_H2;
  return g_H3;
}
template <int ID>
__device__ __forceinline__ u16* sel_bf() {
  if (ID == 1) return g_Bf1;
  if (ID == 2) return g_Bf2;
  return g_Bf3;
}
// width-64 Z/T buffers for layer-3 Horner (carved from H1/H2/H3)
template <int ID>
__device__ __forceinline__ u16* zb() {
  if (ID == 8) return g_H1;                 // Z3
  if (ID == 9) return g_H1 + NN * 64;       // Z2
  if (ID == 10) return g_H2;                // Z1
  if (ID == 11) return g_H2 + NN * 64;      // Z0 (+bias)
  if (ID == 12) return g_H3;                // T ping
  return g_H3 + NN * 64;                    // 13: T pong
}

// -------------------------------------------------------------- dtype probe
__global__ void probe_dtype_kernel(const u16* __restrict__ x) {
  __shared__ int cnt;
  if (threadIdx.x == 0) cnt = 0;
  __syncthreads();
  int c = 0;
  for (int i = threadIdx.x; i < 2048; i += 256) {
    u16 u = x[2 * i];
    int e = (u >> 7) & 0xFF;
    if (e >= 0x8F) c++;
  }
  atomicAdd(&cnt, c);
  __syncthreads();
  if (threadIdx.x == 0) g_f32mode = (cnt > 64) ? 1 : 0;
}

// ---------------------------------------------------------- x -> bf16 convert
__global__ void convert_x_kernel(const void* __restrict__ x) {
  int m = g_f32mode;
  int i = blockIdx.x * 256 + threadIdx.x;  // u32-pair index
  if (i >= NN * 64) return;
  u32 lo = f2bf(ldf(x, 2 * i, m));
  u32 hi = f2bf(ldf(x, 2 * i + 1, m));
  ((u32*)g_X16)[i] = lo | (hi << 16);
}

// ---------------- fused: W1/W2/W3 -> B-frag order, P1 -> B-frag, zero g_deg
template <int FOUT>
__device__ __forceinline__ void conv_w_body(const void* W, u16* dstbuf, int t, int m) {
  constexpr int NT = FOUT / 16;
  if (t >= 1024 * NT) return;
  int lane = t & 63;
  int rest = t >> 6;
  int nt = rest % NT;
  int s = (rest / NT) % 4;
  int kc = rest / (NT * 4);
  int kbase = kc * 128 + s * 32 + ((lane >> 4) << 3);
  int n = nt * 16 + (lane & 15);
  u16* dst = dstbuf + (size_t)t * 8;
#pragma unroll
  for (int j = 0; j < 8; ++j) dst[j] = f2bf(ldf(W, (kbase + j) * FOUT + n, m));
}
__global__ void convert_wp_kernel(const void* __restrict__ W1, const void* __restrict__ W2,
                                  const void* __restrict__ W3, const void* __restrict__ P1) {
  int m = g_f32mode;
  int b = blockIdx.x, tid = threadIdx.x;
  if (b < 32) {
    conv_w_body<128>(W1, g_Bf1, b * 256 + tid, m);
  } else if (b < 64) {
    conv_w_body<128>(W2, g_Bf2, (b - 32) * 256 + tid, m);
  } else if (b < 80) {
    conv_w_body<64>(W3, g_Bf3, (b - 64) * 256 + tid, m);
  } else if (b == 80) {
    int f = tid >> 6, lane = tid & 63;
    int ks = f >> 1, nt = f & 1;
    int quad = lane >> 4, arow = lane & 15;
#pragma unroll
    for (int j = 0; j < 8; ++j)
      g_Pf1[(size_t)tid * 8 + j] =
          f2bf(ldf(P1, (ks * 32 + quad * 8 + j) * 32 + nt * 16 + arow, m));
  } else {
    int i = (b - 81) * 256 + tid;
    if (i < NN) g_deg[i] = 0;
  }
}

// ---------------------------------------------------------------- CSR build
__global__ void count_deg_kernel(const int* __restrict__ dst) {
  int e = blockIdx.x * blockDim.x + threadIdx.x;
  if (e < EE) g_rank[e] = atomicAdd(&g_deg[dst[e]], 1);
}
__global__ __launch_bounds__(256) void deg_partial_kernel() {
  __shared__ int ws[4];
  int b = blockIdx.x, t = threadIdx.x;
  int i = b * 256 + t;
  int v = (i < NN) ? g_deg[i] : 0;
  if (i < NN) g_deg_norm[i] = rsqrtf((float)(v > 0 ? v : 1));
  int x = v;
#pragma unroll
  for (int off = 1; off < 64; off <<= 1) x += __shfl_xor(x, off, 64);
  if ((t & 63) == 0) ws[t >> 6] = x;
  __syncthreads();
  if (t == 0) g_bsum[b] = ws[0] + ws[1] + ws[2] + ws[3];
}
__global__ __launch_bounds__(256) void scan_bsum_kernel() {
  __shared__ int ws[4];
  int t = threadIdx.x;
  int v = (t < NB) ? g_bsum[t] : 0;
  int x = v;
#pragma unroll
  for (int off = 1; off < 64; off <<= 1) {
    int y = __shfl_up(x, off, 64);
    if ((t & 63) >= off) x += y;
  }
  if ((t & 63) == 63) ws[t >> 6] = x;
  __syncthreads();
  int wp = 0;
  if (t >= 64) wp += ws[0];
  if (t >= 128) wp += ws[1];
  if (t >= 192) wp += ws[2];
  if (t < NB) g_boff[t] = wp + x - v;  // exclusive
}
__global__ __launch_bounds__(256) void rowptr_kernel() {
  __shared__ int ws[4];
  int b = blockIdx.x, t = threadIdx.x;
  int i = b * 256 + t;
  int v = (i < NN) ? g_deg[i] : 0;
  int x = v;
#pragma unroll
  for (int off = 1; off < 64; off <<= 1) {
    int y = __shfl_up(x, off, 64);
    if ((t & 63) >= off) x += y;
  }
  if ((t & 63) == 63) ws[t >> 6] = x;
  __syncthreads();
  int wp = g_boff[b];
  if (t >= 64) wp += ws[0];
  if (t >= 128) wp += ws[1];
  if (t >= 192) wp += ws[2];
  if (i < NN) g_row_ptr[i] = wp + x - v;
  if (b == 0 && t == 0) g_row_ptr[NN] = EE;
}
__global__ void fill_csr_kernel(const int* __restrict__ src, const int* __restrict__ dst,
                                const void* __restrict__ w_edge) {
  int m = g_f32mode;
  int e = blockIdx.x * blockDim.x + threadIdx.x;
  if (e >= EE) return;
  int d = dst[e], s = src[e];
  int slot = g_row_ptr[d] + g_rank[e];  // no atomic
  float w = ldf(w_edge, e, m) * g_deg_norm[s];
  g_ecwp[slot] = (u32)s | ((u32)f2bf(w) << 16);
}

// --------------------------------------------------------- width-128 hop (r12)
// out[n][f] = deg_norm[n] * sum_e w[e] * in[col[e]][f]
// one wave per node (4/block); lane = 2 features; 8/4/1 unroll with 16
// independent accumulators -> 8 outstanding 256-B row gathers per wave.
template <int IN_ID, int OUT_ID>
__global__ __launch_bounds__(256) void hop_kernel() {
  int n = blockIdx.x * 4 + (threadIdx.x >> 6);
  if (n >= NN) return;
  int f2 = threadIdx.x & 63;
  const u16* inf = sel_buf<IN_ID>() + 2 * f2;
  int beg = g_row_ptr[n], end = g_row_ptr[n + 1];
  float a0[8], a1[8];
#pragma unroll
  for (int i = 0; i < 8; ++i) { a0[i] = 0.f; a1[i] = 0.f; }
  int e = beg;
  for (; e + 8 <= end; e += 8) {
    u32 p[8];
#pragma unroll
    for (int i = 0; i < 8; ++i) p[i] = g_ecwp[e + i];
    u32 u[8];
#pragma unroll
    for (int i = 0; i < 8; ++i) u[i] = *(const u32*)(inf + (p[i] & 0xFFFFu) * 128);
#pragma unroll
    for (int i = 0; i < 8; ++i) {
      float w = bf2f((u16)(p[i] >> 16));
      a0[i] += w * bf2f((u16)u[i]);
      a1[i] += w * bf2f((u16)(u[i] >> 16));
    }
  }
  for (; e + 4 <= end; e += 4) {
    u32 p[4];
#pragma unroll
    for (int i = 0; i < 4; ++i) p[i] = g_ecwp[e + i];
    u32 u[4];
#pragma unroll
    for (int i = 0; i < 4; ++i) u[i] = *(const u32*)(inf + (p[i] & 0xFFFFu) * 128);
#pragma unroll
    for (int i = 0; i < 4; ++i) {
      float w = bf2f((u16)(p[i] >> 16));
      a0[i] += w * bf2f((u16)u[i]);
      a1[i] += w * bf2f((u16)(u[i] >> 16));
    }
  }
  for (; e < end; ++e) {
    u32 p = g_ecwp[e];
    u32 u = *(const u32*)(inf + (p & 0xFFFFu) * 128);
    float w = bf2f((u16)(p >> 16));
    a0[0] += w * bf2f((u16)u);
    a1[0] += w * bf2f((u16)(u >> 16));
  }
  float s0 = ((a0[0] + a0[1]) + (a0[2] + a0[3])) + ((a0[4] + a0[5]) + (a0[6] + a0[7]));
  float s1 = ((a1[0] + a1[1]) + (a1[2] + a1[3])) + ((a1[4] + a1[5]) + (a1[6] + a1[7]));
  float dn = g_deg_norm[n];
  *(u32*)(sel_buf<OUT_ID>() + n * 128 + 2 * f2) =
      (u32)f2bf(s0 * dn) | ((u32)f2bf(s1 * dn) << 16);
}

// ------------------------------------------------- width-64 hop with addend
// T_out[n] = deg_norm[n] * (A T_in)[n] + Add[n]   (layer-3 Horner step)
// half-wave (32 lanes) per node, 8 nodes/block; 128-B row gathers.
template <int IN_ID, int ADD_ID, int OUT_ID, bool FINAL>
__global__ __launch_bounds__(256) void hop64_kernel(void* __restrict__ outp) {
  int n = blockIdx.x * 8 + (threadIdx.x >> 5);
  if (n >= NN) return;
  int l5 = threadIdx.x & 31;
  const u16* inf = zb<IN_ID>() + 2 * l5;  // stride 64
  int beg = g_row_ptr[n], end = g_row_ptr[n + 1];
  float a0[8], a1[8];
#pragma unroll
  for (int i = 0; i < 8; ++i) { a0[i] = 0.f; a1[i] = 0.f; }
  int e = beg;
  for (; e + 8 <= end; e += 8) {
    u32 p[8];
#pragma unroll
    for (int i = 0; i < 8; ++i) p[i] = g_ecwp[e + i];
    u32 u[8];
#pragma unroll
    for (int i = 0; i < 8; ++i) u[i] = *(const u32*)(inf + (p[i] & 0xFFFFu) * 64);
#pragma unroll
    for (int i = 0; i < 8; ++i) {
      float w = bf2f((u16)(p[i] >> 16));
      a0[i] += w * bf2f((u16)u[i]);
      a1[i] += w * bf2f((u16)(u[i] >> 16));
    }
  }
  for (; e + 4 <= end; e += 4) {
    u32 p[4];
#pragma unroll
    for (int i = 0; i < 4; ++i) p[i] = g_ecwp[e + i];
    u32 u[4];
#pragma unroll
    for (int i = 0; i < 4; ++i) u[i] = *(const u32*)(inf + (p[i] & 0xFFFFu) * 64);
#pragma unroll
    for (int i = 0; i < 4; ++i) {
      float w = bf2f((u16)(p[i] >> 16));
      a0[i] += w * bf2f((u16)u[i]);
      a1[i] += w * bf2f((u16)(u[i] >> 16));
    }
  }
  for (; e < end; ++e) {
    u32 p = g_ecwp[e];
    u32 u = *(const u32*)(inf + (p & 0xFFFFu) * 64);
    float w = bf2f((u16)(p >> 16));
    a0[0] += w * bf2f((u16)u);
    a1[0] += w * bf2f((u16)(u >> 16));
  }
  float s0 = ((a0[0] + a0[1]) + (a0[2] + a0[3])) + ((a0[4] + a0[5]) + (a0[6] + a0[7]));
  float s1 = ((a1[0] + a1[1]) + (a1[2] + a1[3])) + ((a1[4] + a1[5]) + (a1[6] + a1[7]));
  float dn = g_deg_norm[n];
  u32 ad = *(const u32*)(zb<ADD_ID>() + n * 64 + 2 * l5);
  float r0 = s0 * dn + bf2f((u16)ad);
  float r1 = s1 * dn + bf2f((u16)(ad >> 16));
  if (!FINAL) {
    *(u32*)(zb<OUT_ID>() + n * 64 + 2 * l5) = (u32)f2bf(r0) | ((u32)f2bf(r1) << 16);
  } else {
    int ci = n * 64 + 2 * l5;
    *(u32*)(g_Hf16 + ci) = (u32)f2bf(r0) | ((u32)f2bf(r1) << 16);
    if (g_f32mode) {
      ((float*)outp)[2 * PP + ci] = r0;
      ((float*)outp)[2 * PP + ci + 1] = r1;
    } else {
      ((u32*)((u16*)outp + 2 * PP))[ci >> 1] = (u32)f2bf(r0) | ((u32)f2bf(r1) << 16);
    }
  }
}

// -------------------------------------------------- MFMA GEMM (FOUT=128, r12)
// C(M x 128) = [f0 | H1 | H2 | H3] (Mx512, row-major) @ B + bias, ReLU.
// 64 rows/block (wave = one 16-row m-tile), grid 782.
template <int A0_ID, int C_ID, int BF_ID>
__global__ __launch_bounds__(256) void gemm_kernel(const void* __restrict__ bias) {
  constexpr int NT = 8;
  const u16* Bf = sel_bf<BF_ID>();
  int tid = threadIdx.x;
  int lane = tid & 63, wv = tid >> 6;
  int quad = lane >> 4, arow = lane & 15;
  int mbase = blockIdx.x * 64 + wv * 16;
  if (mbase >= NN) return;  // no barriers -> safe (NN % 16 == 0)
  int row0 = mbase + arow;

  f32x4 acc[NT];
#pragma unroll
  for (int nt = 0; nt < NT; ++nt) acc[nt] = (f32x4){0.f, 0.f, 0.f, 0.f};

#pragma unroll
  for (int kc = 0; kc < 4; ++kc) {
    const u16* base = (kc == 0) ? sel_buf<A0_ID>() : (kc == 1) ? g_H1 : (kc == 2) ? g_H2 : g_H3;
#pragma unroll
    for (int s = 0; s < 4; ++s) {
      int ko = s * 32 + quad * 8;
      short8v av = *(const short8v*)(base + row0 * 128 + ko);
      const u16* bp = Bf + (size_t)(((kc * 4 + s) * NT) * 64 + lane) * 8;
#pragma unroll
      for (int nt = 0; nt < NT; ++nt) {
        short8v b = *(const short8v*)(bp + nt * 64 * 8);
        acc[nt] = __builtin_amdgcn_mfma_f32_16x16x32_bf16(av, b, acc[nt], 0, 0, 0);
      }
    }
  }

  int m = g_f32mode;
  float bn[NT];
#pragma unroll
  for (int nt = 0; nt < NT; ++nt) bn[nt] = ldf(bias, nt * 16 + arow, m);
#pragma unroll
  for (int i = 0; i < 4; ++i) {
    int row = mbase + quad * 4 + i;  // C/D: col=lane&15, row=quad*4+reg
#pragma unroll
    for (int nt = 0; nt < NT; ++nt) {
      float v = acc[nt][i] + bn[nt];
      v = v > 0.f ? v : 0.f;  // ReLU (layers 1,2 only)
      sel_buf<C_ID>()[row * 128 + nt * 16 + arow] = f2bf(v);
    }
  }
}

// ------------------------------------- small GEMM: Z_k = Hn1 @ W3[kc] (+bias)
// FOUT=64, K=128 (one kc block of Bf3). Output width-64 Z buffer.
template <int KC, bool BIAS, int OUT_ID>
__global__ __launch_bounds__(256) void gemm64_kernel(const void* __restrict__ bias) {
  int tid = threadIdx.x;
  int lane = tid & 63, wv = tid >> 6;
  int quad = lane >> 4, arow = lane & 15;
  int mbase = blockIdx.x * 64 + wv * 16;
  if (mbase >= NN) return;
  int row0 = mbase + arow;

  f32x4 acc[4];
#pragma unroll
  for (int nt = 0; nt < 4; ++nt) acc[nt] = (f32x4){0.f, 0.f, 0.f, 0.f};

#pragma unroll
  for (int s = 0; s < 4; ++s) {
    int ko = s * 32 + quad * 8;
    short8v av = *(const short8v*)(g_Hn1 + row0 * 128 + ko);
    const u16* bp = g_Bf3 + (size_t)(((KC * 4 + s) * 4) * 64 + lane) * 8;
#pragma unroll
    for (int nt = 0; nt < 4; ++nt) {
      short8v b = *(const short8v*)(bp + nt * 64 * 8);
      acc[nt] = __builtin_amdgcn_mfma_f32_16x16x32_bf16(av, b, acc[nt], 0, 0, 0);
    }
  }

  float bn[4] = {0.f, 0.f, 0.f, 0.f};
  if (BIAS) {
    int m = g_f32mode;
#pragma unroll
    for (int nt = 0; nt < 4; ++nt) bn[nt] = ldf(bias, nt * 16 + arow, m);
  }
  u16* Z = zb<OUT_ID>();
#pragma unroll
  for (int i = 0; i < 4; ++i) {
    int row = mbase + quad * 4 + i;
#pragma unroll
    for (int nt = 0; nt < 4; ++nt)
      Z[row * 64 + nt * 16 + arow] = f2bf(acc[nt][i] + bn[nt]);
  }
}

// ------------------------------------------------------------------ predictor
// MFMA predictor (r11-proven). One wave = 16 pairs.
__global__ __launch_bounds__(256) void predictor_kernel(
    const int* __restrict__ pos_src, const int* __restrict__ pos_dst,
    const int* __restrict__ neg_src, const int* __restrict__ neg_dst,
    const void* __restrict__ pb1, const void* __restrict__ P2,
    const void* __restrict__ pb2, const void* __restrict__ P3, const void* __restrict__ pb3,
    void* __restrict__ out) {
  __shared__ float sP2[32 * 16];
  __shared__ float sb1[32], sb2[16], sP3[16];
  __shared__ float sb3;
  __shared__ float zt[4][16][33];
  int m = g_f32mode;
  int tid = threadIdx.x;
  for (int i = tid; i < 512; i += 256) sP2[i] = ldf(P2, i, m);
  if (tid < 32) sb1[tid] = ldf(pb1, tid, m);
  if (tid < 16) sb2[tid] = ldf(pb2, tid, m);
  if (tid < 16) sP3[tid] = ldf(P3, tid, m);
  if (tid == 0) sb3 = ldf(pb3, 0, m);
  __syncthreads();

  int wv = tid >> 6, lane = tid & 63;
  int quad = lane >> 4, arow = lane & 15;
  int base = (blockIdx.x * 4 + wv) * 16;
  int idx = base + arow;
  int s, d;
  if (idx < PP) { s = pos_src[idx]; d = pos_dst[idx]; }  // PP%16==0 -> wave-uniform
  else          { s = neg_src[idx - PP]; d = neg_dst[idx - PP]; }

  const u16* hs = g_Hf16 + s * 64 + quad * 8;
  const u16* hd = g_Hf16 + d * 64 + quad * 8;
  short8v zf[2];
#pragma unroll
  for (int ks = 0; ks < 2; ++ks) {
    short8v a = *(const short8v*)(hs + ks * 32);
    short8v b = *(const short8v*)(hd + ks * 32);
#pragma unroll
    for (int j = 0; j < 8; ++j)
      ((u16*)&zf[ks])[j] = f2bf(bf2f((u16)a[j]) * bf2f((u16)b[j]));
  }
  f32x4 acc[2];
  acc[0] = (f32x4){0.f, 0.f, 0.f, 0.f};
  acc[1] = (f32x4){0.f, 0.f, 0.f, 0.f};
#pragma unroll
  for (int ks = 0; ks < 2; ++ks) {
#pragma unroll
    for (int nt = 0; nt < 2; ++nt) {
      short8v bfr = *(const short8v*)(g_Pf1 + (size_t)((ks * 2 + nt) * 64 + lane) * 8);
      acc[nt] = __builtin_amdgcn_mfma_f32_16x16x32_bf16(zf[ks], bfr, acc[nt], 0, 0, 0);
    }
  }
#pragma unroll
  for (int nt = 0; nt < 2; ++nt) {
    float bn = sb1[nt * 16 + arow];
#pragma unroll
    for (int i = 0; i < 4; ++i) {
      float v = acc[nt][i] + bn;
      zt[wv][quad * 4 + i][nt * 16 + arow] = v > 0.f ? v : 0.2f * v;
    }
  }
  __syncthreads();
  float z2[4];
#pragma unroll
  for (int jj = 0; jj < 4; ++jj) z2[jj] = sb2[quad * 4 + jj];
  const float* zrow = &zt[wv][arow][0];
#pragma unroll
  for (int c = 0; c < 32; ++c) {
    float zc = zrow[c];
#pragma unroll
    for (int jj = 0; jj < 4; ++jj) z2[jj] += zc * sP2[c * 16 + quad * 4 + jj];
  }
  float o = 0.f;
#pragma unroll
  for (int jj = 0; jj < 4; ++jj) {
    float v = z2[jj] > 0.f ? z2[jj] : 0.2f * z2[jj];
    o += v * sP3[quad * 4 + jj];
  }
  o += __shfl_xor(o, 16, 64);
  o += __shfl_xor(o, 32, 64);
  o += sb3;
  if (quad == 0) {
    if (m) ((float*)out)[idx] = o;
    else   ((u16*)out)[idx] = f2bf(o);
  }
}

// ------------------------------------------------------------------- launch
extern "C" void kernel_launch(void* const* d_in, const int* in_sizes, int n_in,
                              void* d_out, int out_size, void* d_ws, size_t ws_size,
                              hipStream_t stream) {
  const u16* x       = (const u16*)d_in[0];
  const int* src     = (const int*)d_in[1];
  const int* dst     = (const int*)d_in[2];
  const void* w_edge = d_in[3];
  const int* pos_src = (const int*)d_in[4];
  const int* pos_dst = (const int*)d_in[5];
  const int* neg_src = (const int*)d_in[6];
  const int* neg_dst = (const int*)d_in[7];
  const void* W1 = d_in[8];
  const void* b1 = d_in[9];
  const void* W2 = d_in[10];
  const void* b2 = d_in[11];
  const void* W3 = d_in[12];
  const void* b3 = d_in[13];
  const void* P1  = d_in[14];
  const void* pb1 = d_in[15];
  const void* P2  = d_in[16];
  const void* pb2 = d_in[17];
  const void* P3  = d_in[18];
  const void* pb3 = d_in[19];
  (void)d_ws; (void)ws_size; (void)in_sizes; (void)n_in; (void)out_size;

  // --- probe + pre-conversion (fused) + CSR build ---
  probe_dtype_kernel<<<1, 256, 0, stream>>>(x);
  convert_x_kernel<<<(NN * 64 + 255) / 256, 256, 0, stream>>>(x);
  convert_wp_kernel<<<81 + NB, 256, 0, stream>>>(W1, W2, W3, P1);  // + zero g_deg
  count_deg_kernel<<<(EE + 255) / 256, 256, 0, stream>>>(dst);
  deg_partial_kernel<<<NB, 256, 0, stream>>>();
  scan_bsum_kernel<<<1, 256, 0, stream>>>();
  rowptr_kernel<<<NB, 256, 0, stream>>>();
  fill_csr_kernel<<<(EE + 255) / 256, 256, 0, stream>>>(src, dst, w_edge);

  int gHop = (NN + 3) / 4;
  int gHop64 = (NN + 7) / 8;
  int gGemm = (NN + 63) / 64;

  // --- Layer 1: f0 = x(bf16) ---
  hop_kernel<0, 5><<<gHop, 256, 0, stream>>>();
  hop_kernel<5, 6><<<gHop, 256, 0, stream>>>();
  hop_kernel<6, 7><<<gHop, 256, 0, stream>>>();
  gemm_kernel<0, 3, 1><<<gGemm, 256, 0, stream>>>(b1);

  // --- Layer 2: f0 = Hn0 ---
  hop_kernel<3, 5><<<gHop, 256, 0, stream>>>();
  hop_kernel<5, 6><<<gHop, 256, 0, stream>>>();
  hop_kernel<6, 7><<<gHop, 256, 0, stream>>>();
  gemm_kernel<3, 4, 2><<<gGemm, 256, 0, stream>>>(b2);

  // --- Layer 3 (Horner): out = Z0+b3 + A(Z1 + A(Z2 + A Z3)), Z_k = Hn1@W3_k ---
  gemm64_kernel<3, false, 8><<<gGemm, 256, 0, stream>>>(nullptr);   // Z3
  gemm64_kernel<2, false, 9><<<gGemm, 256, 0, stream>>>(nullptr);   // Z2
  gemm64_kernel<1, false, 10><<<gGemm, 256, 0, stream>>>(nullptr);  // Z1
  gemm64_kernel<0, true, 11><<<gGemm, 256, 0, stream>>>(b3);        // Z0 + b3
  hop64_kernel<8, 9, 12, false><<<gHop64, 256, 0, stream>>>(nullptr);   // T1 = A Z3 + Z2
  hop64_kernel<12, 10, 13, false><<<gHop64, 256, 0, stream>>>(nullptr); // T2 = A T1 + Z1
  hop64_kernel<13, 11, 12, true><<<gHop64, 256, 0, stream>>>(d_out);    // h = A T2 + Z0

  // --- Predictor (pos+neg fused, MFMA) ---
  predictor_kernel<<<(2 * PP) / (4 * 16), 256, 0, stream>>>(pos_src, pos_dst, neg_src, neg_dst,
                                                            pb1, P2, pb2, P3, pb3, d_out);
}